// Round 1
// baseline (562.761 us; speedup 1.0000x reference)
//
#include <hip/hip_runtime.h>
#include <hip/hip_bf16.h>

// Problem constants (from reference)
#define NB 4       // batch
#define CIN 32
#define TT 8       // time steps
#define NN 2000    // nodes
#define NE 16000   // edges
#define H1C 128
#define H2C 256
#define COUT 64
#define BT (NB*TT) // 32 graph replicas

// ---------------- prep kernels ----------------

__global__ __launch_bounds__(256) void k_init(float* deg, int* cnt) {
    int n = blockIdx.x * 256 + threadIdx.x;
    if (n < 2048) { deg[n] = 1.0f; cnt[n] = 0; }   // self-loop weight 1
}

__global__ __launch_bounds__(256) void k_count(const int* __restrict__ dst,
                                               const float* __restrict__ ew,
                                               float* deg, int* cnt) {
    int e = blockIdx.x * 256 + threadIdx.x;
    if (e < NE) {
        int d = dst[e];
        atomicAdd(&deg[d], ew[e]);
        atomicAdd(&cnt[d], 1);
    }
}

__global__ __launch_bounds__(256) void k_dinv(const float* __restrict__ deg,
                                              float* dinv, float* selfn) {
    int n = blockIdx.x * 256 + threadIdx.x;
    if (n < NN) {
        float di = 1.0f / sqrtf(deg[n]);   // precise (deg >= 1)
        dinv[n] = di;
        selfn[n] = di * di;                // self-loop norm: dinv*1*dinv
    }
}

// single-block exclusive scan of cnt[0..NN) -> rowptr[0..NN], cur copy
__global__ __launch_bounds__(256) void k_scan(const int* __restrict__ cnt,
                                              int* rowptr, int* cur) {
    __shared__ int s[256];
    int tid = threadIdx.x;
    int base = tid * 8;
    int local[8];
    int sum = 0;
    #pragma unroll
    for (int i = 0; i < 8; i++) {
        int idx = base + i;
        int v = (idx < NN) ? cnt[idx] : 0;
        local[i] = sum;         // exclusive within chunk
        sum += v;
    }
    s[tid] = sum;
    __syncthreads();
    for (int off = 1; off < 256; off <<= 1) {
        int v = 0;
        if (tid >= off) v = s[tid - off];
        __syncthreads();
        if (tid >= off) s[tid] += v;
        __syncthreads();
    }
    int chunk_excl = (tid > 0) ? s[tid - 1] : 0;
    #pragma unroll
    for (int i = 0; i < 8; i++) {
        int idx = base + i;
        if (idx < NN) {
            int rp = chunk_excl + local[i];
            rowptr[idx] = rp;
            cur[idx] = rp;
        }
    }
    if (tid == 255) rowptr[NN] = s[255];
}

__global__ __launch_bounds__(256) void k_fill(const int* __restrict__ src,
                                              const int* __restrict__ dst,
                                              const float* __restrict__ ew,
                                              const float* __restrict__ dinv,
                                              int* cur, int* col, float* val) {
    int e = blockIdx.x * 256 + threadIdx.x;
    if (e < NE) {
        int sN = src[e], d = dst[e];
        int pos = atomicAdd(&cur[d], 1);
        col[pos] = sN;
        val[pos] = dinv[sN] * ew[e] * dinv[d];
    }
}

// ---------------- gather (S * h), channel-major ----------------
// in element (c,n) at: b*ibs + t*its + c*iks + n ; same form for out.
__global__ __launch_bounds__(256) void k_gather(
    const float* __restrict__ in, float* __restrict__ out,
    const int* __restrict__ rowptr, const int* __restrict__ col,
    const float* __restrict__ val, const float* __restrict__ selfn,
    const float* __restrict__ bias, int relu,
    int ibs, int its, int iks, int obs, int ots, int oks)
{
    int n = blockIdx.x * 256 + threadIdx.x;
    if (n >= NN) return;
    int c = blockIdx.y;
    int bt = blockIdx.z;
    int b = bt >> 3, t = bt & 7;
    const float* ip = in + b * ibs + t * its + c * iks;
    float acc = selfn[n] * ip[n];
    int p0 = rowptr[n], p1 = rowptr[n + 1];
    for (int p = p0; p < p1; p++)
        acc += val[p] * ip[col[p]];
    if (bias) acc += bias[c];
    if (relu) acc = fmaxf(acc, 0.0f);
    out[b * obs + t * ots + c * oks + n] = acc;
}

// ---------------- GEMM: O[c,n] = sum_k A[k,n]*W[k,c] (+bias), channel-major ----------------
// A element (k,n): b*abs_ + t*ats_ + k*aks_ + n
// O element (c,n): b*obs_ + t*ots_ + c*oks_ + n
__global__ __launch_bounds__(256) void k_gemm(
    const float* __restrict__ A, const float* __restrict__ W,
    const float* __restrict__ bias, float* __restrict__ O,
    int K, int NC,
    int abs_, int ats_, int aks_,
    int obs_, int ots_, int oks_)
{
    __shared__ float As[16][68];
    __shared__ float Bs[16][64];
    const int tid = threadIdx.x;
    const int mt = blockIdx.x;   // n-tile (0..31)
    const int ct = blockIdx.y;   // cout-tile
    const int bt = blockIdx.z;   // 0..31
    const int b = bt >> 3, t = bt & 7;
    const int n0 = mt * 64;
    const int c0 = ct * 64;
    const int tx = tid & 15, ty = tid >> 4;
    const float* Abase = A + b * abs_ + t * ats_;
    const float* Wbase = W + c0;

    float acc[4][4] = {};

    for (int k0 = 0; k0 < K; k0 += 16) {
        #pragma unroll
        for (int i = 0; i < 4; i++) {
            int idx = tid + i * 256;
            int m = idx & 63, kk = idx >> 6;
            int n = n0 + m;
            As[kk][m] = (n < NN) ? Abase[(k0 + kk) * aks_ + n] : 0.0f;
        }
        #pragma unroll
        for (int i = 0; i < 4; i++) {
            int idx = tid + i * 256;
            int c = idx & 63, kk = idx >> 6;
            Bs[kk][c] = Wbase[(k0 + kk) * NC + c];
        }
        __syncthreads();
        #pragma unroll
        for (int kk = 0; kk < 16; kk++) {
            float4 av = *reinterpret_cast<const float4*>(&As[kk][ty * 4]);
            float4 bv = *reinterpret_cast<const float4*>(&Bs[kk][tx * 4]);
            float a[4] = { av.x, av.y, av.z, av.w };
            float bb[4] = { bv.x, bv.y, bv.z, bv.w };
            #pragma unroll
            for (int i = 0; i < 4; i++)
                #pragma unroll
                for (int j = 0; j < 4; j++)
                    acc[i][j] += a[i] * bb[j];
        }
        __syncthreads();
    }

    float* Obase = O + b * obs_ + t * ots_;
    int nrow = n0 + ty * 4;
    if (nrow + 3 < NN) {
        #pragma unroll
        for (int j = 0; j < 4; j++) {
            int c = c0 + tx * 4 + j;
            float bb = bias ? bias[c] : 0.0f;
            float4 v = make_float4(acc[0][j] + bb, acc[1][j] + bb,
                                   acc[2][j] + bb, acc[3][j] + bb);
            *reinterpret_cast<float4*>(&Obase[c * oks_ + nrow]) = v;
        }
    }
}

// ---------------- launch ----------------

extern "C" void kernel_launch(void* const* d_in, const int* in_sizes, int n_in,
                              void* d_out, int out_size, void* d_ws, size_t ws_size,
                              hipStream_t stream) {
    (void)in_sizes; (void)n_in; (void)out_size; (void)ws_size;

    const float* x  = (const float*)d_in[0];
    const int*   ei = (const int*)d_in[1];
    const float* ew = (const float*)d_in[2];
    const float* W1 = (const float*)d_in[3];
    const float* b1 = (const float*)d_in[4];
    const float* W2 = (const float*)d_in[5];
    const float* b2 = (const float*)d_in[6];
    const float* W3 = (const float*)d_in[7];
    const float* b3 = (const float*)d_in[8];
    float* out = (float*)d_out;

    const int* src = ei;
    const int* dst = ei + NE;

    // workspace layout (float offsets)
    float* ws    = (float*)d_ws;
    float* deg   = ws;                 // 2048
    float* dinv  = ws + 2048;          // 2048
    float* selfn = ws + 4096;          // 2048
    float* val   = ws + 6144;          // NE
    int*   cnt   = (int*)(ws + 6144 + NE);          // 2048
    int*   cur   = cnt + 2048;                      // 2048
    int*   rowptr= cur + 2048;                      // 2048 (need NN+1)
    int*   col   = rowptr + 2048;                   // NE
    float* bufA  = ws + 6144 + NE + 2048*3 + NE;    // up to 32*128*2000 floats
    float* bufH  = bufA + (size_t)BT * 128 * NN;    // up to 32*256*2000 floats

    // prep
    k_init <<<dim3(8), dim3(256), 0, stream>>>(deg, cnt);
    k_count<<<dim3((NE + 255) / 256), dim3(256), 0, stream>>>(dst, ew, deg, cnt);
    k_dinv <<<dim3(8), dim3(256), 0, stream>>>(deg, dinv, selfn);
    k_scan <<<dim3(1), dim3(256), 0, stream>>>(cnt, rowptr, cur);
    k_fill <<<dim3((NE + 255) / 256), dim3(256), 0, stream>>>(src, dst, ew, dinv, cur, col, val);

    // layer 1: A1 = S*x  (32 ch), H1 = A1@W1 + b1 (128 ch)
    // x element (c,n): b*512000 + t*2000 + c*16000 + n
    k_gather<<<dim3(8, CIN, BT), dim3(256), 0, stream>>>(
        x, bufA, rowptr, col, val, selfn, nullptr, 0,
        CIN*TT*NN, NN, TT*NN,        // in: b,t,c strides for x
        TT*CIN*NN, CIN*NN, NN);      // out: A1 [bt][32][2000]
    k_gemm<<<dim3(32, H1C / 64, BT), dim3(256), 0, stream>>>(
        bufA, W1, b1, bufH, CIN, H1C,
        TT*CIN*NN, CIN*NN, NN,
        TT*H1C*NN, H1C*NN, NN);

    // layer 2: A2 = S*H1 (128 ch), H2 = A2@W2 + b2 (256 ch)
    k_gather<<<dim3(8, H1C, BT), dim3(256), 0, stream>>>(
        bufH, bufA, rowptr, col, val, selfn, nullptr, 0,
        TT*H1C*NN, H1C*NN, NN,
        TT*H1C*NN, H1C*NN, NN);
    k_gemm<<<dim3(32, H2C / 64, BT), dim3(256), 0, stream>>>(
        bufA, W2, b2, bufH, H1C, H2C,
        TT*H1C*NN, H1C*NN, NN,
        TT*H2C*NN, H2C*NN, NN);

    // layer 3: T3 = H2@W3 (64 ch, no bias), out = relu(S*T3 + b3) transposed
    k_gemm<<<dim3(32, COUT / 64, BT), dim3(256), 0, stream>>>(
        bufH, W3, nullptr, bufA, H2C, COUT,
        TT*H2C*NN, H2C*NN, NN,
        TT*COUT*NN, COUT*NN, NN);
    // out element (c,n): b*1024000 + t*2000 + c*16000 + n   ([B][COUT][T][N])
    k_gather<<<dim3(8, COUT, BT), dim3(256), 0, stream>>>(
        bufA, out, rowptr, col, val, selfn, b3, 1,
        TT*COUT*NN, COUT*NN, NN,
        COUT*TT*NN, NN, TT*NN);
}

// Round 2
// 267.399 us; speedup vs baseline: 2.1046x; 2.1046x over previous
//
#include <hip/hip_runtime.h>
#include <hip/hip_bf16.h>

// Problem constants (from reference)
#define NB 4       // batch
#define CIN 32
#define TT 8       // time steps
#define NN 2000    // nodes
#define NE 16000   // edges
#define H1C 128
#define H2C 256
#define COUT 64
#define BT (NB*TT) // 32 graph replicas
#define M_ROWS (BT*NN) // 64000

// ---------------- prep kernels ----------------

__global__ __launch_bounds__(256) void k_init(float* deg, int* cnt) {
    int n = blockIdx.x * 256 + threadIdx.x;
    if (n < 2048) { deg[n] = 1.0f; cnt[n] = 0; }   // self-loop weight 1
}

__global__ __launch_bounds__(256) void k_count(const int* __restrict__ dst,
                                               const float* __restrict__ ew,
                                               float* deg, int* cnt) {
    int e = blockIdx.x * 256 + threadIdx.x;
    if (e < NE) {
        int d = dst[e];
        atomicAdd(&deg[d], ew[e]);
        atomicAdd(&cnt[d], 1);
    }
}

__global__ __launch_bounds__(256) void k_dinv(const float* __restrict__ deg,
                                              float* dinv, float* selfn) {
    int n = blockIdx.x * 256 + threadIdx.x;
    if (n < NN) {
        float di = 1.0f / sqrtf(deg[n]);
        dinv[n] = di;
        selfn[n] = di * di;
    }
}

__global__ __launch_bounds__(256) void k_scan(const int* __restrict__ cnt,
                                              int* rowptr, int* cur) {
    __shared__ int s[256];
    int tid = threadIdx.x;
    int base = tid * 8;
    int local[8];
    int sum = 0;
    #pragma unroll
    for (int i = 0; i < 8; i++) {
        int idx = base + i;
        int v = (idx < NN) ? cnt[idx] : 0;
        local[i] = sum;
        sum += v;
    }
    s[tid] = sum;
    __syncthreads();
    for (int off = 1; off < 256; off <<= 1) {
        int v = 0;
        if (tid >= off) v = s[tid - off];
        __syncthreads();
        if (tid >= off) s[tid] += v;
        __syncthreads();
    }
    int chunk_excl = (tid > 0) ? s[tid - 1] : 0;
    #pragma unroll
    for (int i = 0; i < 8; i++) {
        int idx = base + i;
        if (idx < NN) {
            int rp = chunk_excl + local[i];
            rowptr[idx] = rp;
            cur[idx] = rp;
        }
    }
    if (tid == 255) rowptr[NN] = s[255];
}

__global__ __launch_bounds__(256) void k_fill(const int* __restrict__ src,
                                              const int* __restrict__ dst,
                                              const float* __restrict__ ew,
                                              const float* __restrict__ dinv,
                                              int* cur, int* col, float* val) {
    int e = blockIdx.x * 256 + threadIdx.x;
    if (e < NE) {
        int sN = src[e], d = dst[e];
        int pos = atomicAdd(&cur[d], 1);
        col[pos] = sN;
        val[pos] = dinv[sN] * ew[e] * dinv[d];
    }
}

// ---------------- input transpose: x [B][CIN][T][N] -> xt [bt][n][CIN] ----------------
__global__ __launch_bounds__(256) void k_tin(const float* __restrict__ x,
                                             float* __restrict__ xt) {
    __shared__ float s[CIN][65];
    int tid = threadIdx.x;
    int bt = blockIdx.y, b = bt >> 3, t = bt & 7;
    int n0 = blockIdx.x * 64;
    const float* xp = x + ((size_t)b * CIN * TT + t) * NN;
    #pragma unroll
    for (int pass = 0; pass < 8; pass++) {
        int c = (tid >> 6) + pass * 4;
        int n = n0 + (tid & 63);
        s[c][tid & 63] = (n < NN) ? xp[(size_t)c * TT * NN + n] : 0.f;
    }
    __syncthreads();
    #pragma unroll
    for (int pass = 0; pass < 8; pass++) {
        int nn = (tid >> 5) + pass * 8;
        int n = n0 + nn;
        if (n < NN) xt[((size_t)bt * NN + n) * CIN + (tid & 31)] = s[tid & 31][nn];
    }
}

// ---------------- node-major gathers: out_row[n] = selfn[n]*in_row[n] + sum val*in_row[col] ----------------

// C=32: half-wave, 2 edges per iteration
__global__ __launch_bounds__(256) void k_gather32(
    const float* __restrict__ in, float* __restrict__ out,
    const int* __restrict__ rowptr, const int* __restrict__ col,
    const float* __restrict__ val, const float* __restrict__ selfn)
{
    int tid = threadIdx.x;
    int lane = tid & 63, wid = tid >> 6;
    int n = blockIdx.x * 4 + wid;
    int bt = blockIdx.y;
    int c = lane & 31, half = lane >> 5;
    const float* ip = in + (size_t)bt * NN * CIN;
    int p0 = rowptr[n], p1 = rowptr[n + 1];
    float acc = half ? 0.f : selfn[n] * ip[(size_t)n * CIN + c];
    for (int p = p0 + half; p < p1; p += 2)
        acc += val[p] * ip[(size_t)col[p] * CIN + c];
    acc += __shfl_xor(acc, 32);
    if (half == 0) out[((size_t)bt * NN + n) * CIN + c] = acc;
}

// C=128: full wave, float2 per lane, 2 edges unrolled
__global__ __launch_bounds__(256) void k_gather128(
    const float2* __restrict__ in, float2* __restrict__ out,
    const int* __restrict__ rowptr, const int* __restrict__ col,
    const float* __restrict__ val, const float* __restrict__ selfn)
{
    int tid = threadIdx.x;
    int lane = tid & 63, wid = tid >> 6;
    int n = blockIdx.x * 4 + wid;
    int bt = blockIdx.y;
    const float2* ip = in + (size_t)bt * NN * 64;   // 64 float2 per row
    int p0 = rowptr[n], p1 = rowptr[n + 1];
    float sn = selfn[n];
    float2 v = ip[(size_t)n * 64 + lane];
    float ax = sn * v.x, ay = sn * v.y;
    int p = p0;
    for (; p + 1 < p1; p += 2) {
        int s0 = col[p], s1 = col[p + 1];
        float w0 = val[p], w1 = val[p + 1];
        float2 u0 = ip[(size_t)s0 * 64 + lane];
        float2 u1 = ip[(size_t)s1 * 64 + lane];
        ax += w0 * u0.x + w1 * u1.x;
        ay += w0 * u0.y + w1 * u1.y;
    }
    if (p < p1) {
        float w = val[p];
        float2 u = ip[(size_t)col[p] * 64 + lane];
        ax += w * u.x; ay += w * u.y;
    }
    float2 o; o.x = ax; o.y = ay;
    out[((size_t)bt * NN + n) * 64 + lane] = o;
}

// C=64 final gather + bias + relu + transposed write to out[B][COUT][T][N]
__global__ __launch_bounds__(256) void k_gather_out(
    const float* __restrict__ in, float* __restrict__ out,
    const int* __restrict__ rowptr, const int* __restrict__ col,
    const float* __restrict__ val, const float* __restrict__ selfn,
    const float* __restrict__ bias)
{
    __shared__ float s[64][65];
    int tid = threadIdx.x;
    int lane = tid & 63, wid = tid >> 6;
    int bt = blockIdx.y, b = bt >> 3, t = bt & 7;
    int n0 = blockIdx.x * 64;
    const float* ip = in + (size_t)bt * NN * COUT;
    float bc = bias[lane];
    for (int k = 0; k < 16; k++) {
        int nn = wid * 16 + k;
        int n = n0 + nn;
        float r = 0.f;
        if (n < NN) {
            int p0 = rowptr[n], p1 = rowptr[n + 1];
            float acc = selfn[n] * ip[(size_t)n * COUT + lane];
            int p = p0;
            for (; p + 1 < p1; p += 2) {
                int s0 = col[p], s1 = col[p + 1];
                float w0 = val[p], w1 = val[p + 1];
                acc += w0 * ip[(size_t)s0 * COUT + lane]
                     + w1 * ip[(size_t)s1 * COUT + lane];
            }
            if (p < p1) acc += val[p] * ip[(size_t)col[p] * COUT + lane];
            r = fmaxf(acc + bc, 0.f);
        }
        s[nn][lane] = r;
    }
    __syncthreads();
    // write coalesced along n: out[((b*COUT + c)*TT + t)*NN + n]
    #pragma unroll
    for (int pass = 0; pass < 16; pass++) {
        int c = wid + pass * 4;
        int n = n0 + lane;
        if (n < NN)
            out[(((size_t)b * COUT + c) * TT + t) * NN + n] = s[lane][c];
    }
}

// ---------------- row-major GEMM: O[m][c] = sum_k A[m][k] W[k][c] (+bias) ----------------
template<int BM, int BN, int BK, int TM, int TN, int K, int NC>
__global__ __launch_bounds__(256) void k_gemm_rm(
    const float* __restrict__ A, const float* __restrict__ W,
    const float* __restrict__ bias, float* __restrict__ O)
{
    __shared__ float As[BK][BM + 4];
    __shared__ float Ws[BK][BN];
    const int tid = threadIdx.x;
    const int m0 = blockIdx.x * BM;
    const int c0 = blockIdx.y * BN;
    const int tx = tid % (BN / TN);
    const int ty = tid / (BN / TN);

    float acc[TM][TN] = {};

    for (int k0 = 0; k0 < K; k0 += BK) {
        // A tile: BM x BK, float4 along k, store transposed into As[k][m]
        constexpr int AP = (BM * BK / 4) / 256;
        #pragma unroll
        for (int i = 0; i < AP; i++) {
            int idx = tid + i * 256;
            int k4 = idx & (BK / 4 - 1);
            int m  = idx / (BK / 4);
            float4 v = *reinterpret_cast<const float4*>(
                &A[(size_t)(m0 + m) * K + k0 + k4 * 4]);
            As[k4 * 4 + 0][m] = v.x;
            As[k4 * 4 + 1][m] = v.y;
            As[k4 * 4 + 2][m] = v.z;
            As[k4 * 4 + 3][m] = v.w;
        }
        // W tile: BK x BN, float4 along c
        constexpr int WP = (BK * BN / 4) / 256;
        #pragma unroll
        for (int i = 0; i < WP; i++) {
            int idx = tid + i * 256;
            int c4 = idx & (BN / 4 - 1);
            int kk = idx / (BN / 4);
            *reinterpret_cast<float4*>(&Ws[kk][c4 * 4]) =
                *reinterpret_cast<const float4*>(
                    &W[(size_t)(k0 + kk) * NC + c0 + c4 * 4]);
        }
        __syncthreads();
        #pragma unroll
        for (int kk = 0; kk < BK; kk++) {
            float af[TM], bf[TN];
            #pragma unroll
            for (int i = 0; i < TM; i += 4)
                *reinterpret_cast<float4*>(&af[i]) =
                    *reinterpret_cast<const float4*>(&As[kk][ty * TM + i]);
            #pragma unroll
            for (int j = 0; j < TN; j += 4)
                *reinterpret_cast<float4*>(&bf[j]) =
                    *reinterpret_cast<const float4*>(&Ws[kk][tx * TN + j]);
            #pragma unroll
            for (int i = 0; i < TM; i++)
                #pragma unroll
                for (int j = 0; j < TN; j++)
                    acc[i][j] += af[i] * bf[j];
        }
        __syncthreads();
    }

    float bb[TN];
    #pragma unroll
    for (int j = 0; j < TN; j++) bb[j] = bias ? bias[c0 + tx * TN + j] : 0.f;
    #pragma unroll
    for (int i = 0; i < TM; i++) {
        int m = m0 + ty * TM + i;
        #pragma unroll
        for (int j = 0; j < TN; j += 4) {
            float4 v = make_float4(acc[i][j] + bb[j],   acc[i][j+1] + bb[j+1],
                                   acc[i][j+2] + bb[j+2], acc[i][j+3] + bb[j+3]);
            *reinterpret_cast<float4*>(&O[(size_t)m * NC + c0 + tx * TN + j]) = v;
        }
    }
}

// ---------------- launch ----------------

extern "C" void kernel_launch(void* const* d_in, const int* in_sizes, int n_in,
                              void* d_out, int out_size, void* d_ws, size_t ws_size,
                              hipStream_t stream) {
    (void)in_sizes; (void)n_in; (void)out_size; (void)ws_size;

    const float* x  = (const float*)d_in[0];
    const int*   ei = (const int*)d_in[1];
    const float* ew = (const float*)d_in[2];
    const float* W1 = (const float*)d_in[3];
    const float* b1 = (const float*)d_in[4];
    const float* W2 = (const float*)d_in[5];
    const float* b2 = (const float*)d_in[6];
    const float* W3 = (const float*)d_in[7];
    const float* b3 = (const float*)d_in[8];
    float* out = (float*)d_out;

    const int* src = ei;
    const int* dst = ei + NE;

    // workspace layout (float offsets)
    float* ws    = (float*)d_ws;
    float* deg   = ws;                  // 2048
    float* dinv  = ws + 2048;           // 2048
    float* selfn = ws + 4096;           // 2048
    float* val   = ws + 6144;           // NE
    int*   cnt   = (int*)(ws + 6144 + NE);   // 2048
    int*   cur   = cnt + 2048;               // 2048
    int*   rowptr= cur + 2048;               // 2048 (NN+1 used)
    int*   col   = rowptr + 2048;            // NE
    float* bufA  = ws + 6144 + NE + 2048 * 3 + NE;       // 32*2000*128 floats max
    float* bufH  = bufA + (size_t)BT * NN * 128;         // 32*2000*256 floats
    float* xt    = bufH + (size_t)BT * NN * 128;         // upper half of bufH (2.05M floats)

    // prep
    k_init <<<dim3(8), dim3(256), 0, stream>>>(deg, cnt);
    k_count<<<dim3((NE + 255) / 256), dim3(256), 0, stream>>>(dst, ew, deg, cnt);
    k_dinv <<<dim3(8), dim3(256), 0, stream>>>(deg, dinv, selfn);
    k_scan <<<dim3(1), dim3(256), 0, stream>>>(cnt, rowptr, cur);
    k_fill <<<dim3((NE + 255) / 256), dim3(256), 0, stream>>>(src, dst, ew, dinv, cur, col, val);

    // input transpose -> node-major xt [bt][n][32]
    k_tin<<<dim3(32, BT), dim3(256), 0, stream>>>(x, xt);

    // layer 1: A1 = S*xt (32ch), H1 = A1@W1 + b1 (128ch)
    k_gather32<<<dim3(NN / 4, BT), dim3(256), 0, stream>>>(xt, bufA, rowptr, col, val, selfn);
    k_gemm_rm<128, 64, 16, 8, 4, CIN, H1C>
        <<<dim3(M_ROWS / 128, H1C / 64), dim3(256), 0, stream>>>(bufA, W1, b1, bufH);

    // layer 2: A2 = S*H1 (128ch), H2 = A2@W2 + b2 (256ch)
    k_gather128<<<dim3(NN / 4, BT), dim3(256), 0, stream>>>(
        (const float2*)bufH, (float2*)bufA, rowptr, col, val, selfn);
    k_gemm_rm<128, 128, 16, 8, 8, H1C, H2C>
        <<<dim3(M_ROWS / 128, H2C / 128), dim3(256), 0, stream>>>(bufA, W2, b2, bufH);

    // layer 3: T3 = H2@W3 (64ch, no bias); out = relu(S*T3 + b3), transposed write
    k_gemm_rm<128, 64, 16, 8, 4, H2C, COUT>
        <<<dim3(M_ROWS / 128, COUT / 64), dim3(256), 0, stream>>>(bufH, W3, nullptr, bufA);
    k_gather_out<<<dim3((NN + 63) / 64, BT), dim3(256), 0, stream>>>(
        bufA, out, rowptr, col, val, selfn, b3);
}

// Round 3
// 159.674 us; speedup vs baseline: 3.5244x; 1.6746x over previous
//
#include <hip/hip_runtime.h>
#include <hip/hip_bf16.h>

// Problem constants (from reference)
#define NB 4       // batch
#define CIN 32
#define TT 8       // time steps
#define NN 2000    // nodes
#define NE 16000   // edges
#define H1C 128
#define H2C 256
#define COUT 64
#define BT (NB*TT) // 32 graph replicas

// ---------------- prep kernels ----------------

__global__ __launch_bounds__(256) void k_init(float* deg, int* cnt) {
    int n = blockIdx.x * 256 + threadIdx.x;
    if (n < 2048) { deg[n] = 1.0f; cnt[n] = 0; }   // self-loop weight 1
}

__global__ __launch_bounds__(256) void k_count(const int* __restrict__ dst,
                                               const float* __restrict__ ew,
                                               float* deg, int* cnt) {
    int e = blockIdx.x * 256 + threadIdx.x;
    if (e < NE) {
        int d = dst[e];
        atomicAdd(&deg[d], ew[e]);
        atomicAdd(&cnt[d], 1);
    }
}

__global__ __launch_bounds__(256) void k_dinv(const float* __restrict__ deg,
                                              float* dinv, float* selfn) {
    int n = blockIdx.x * 256 + threadIdx.x;
    if (n < NN) {
        float di = 1.0f / sqrtf(deg[n]);
        dinv[n] = di;
        selfn[n] = di * di;
    }
}

__global__ __launch_bounds__(256) void k_scan(const int* __restrict__ cnt,
                                              int* rowptr, int* cur) {
    __shared__ int s[256];
    int tid = threadIdx.x;
    int base = tid * 8;
    int local[8];
    int sum = 0;
    #pragma unroll
    for (int i = 0; i < 8; i++) {
        int idx = base + i;
        int v = (idx < NN) ? cnt[idx] : 0;
        local[i] = sum;
        sum += v;
    }
    s[tid] = sum;
    __syncthreads();
    for (int off = 1; off < 256; off <<= 1) {
        int v = 0;
        if (tid >= off) v = s[tid - off];
        __syncthreads();
        if (tid >= off) s[tid] += v;
        __syncthreads();
    }
    int chunk_excl = (tid > 0) ? s[tid - 1] : 0;
    #pragma unroll
    for (int i = 0; i < 8; i++) {
        int idx = base + i;
        if (idx < NN) {
            int rp = chunk_excl + local[i];
            rowptr[idx] = rp;
            cur[idx] = rp;
        }
    }
    if (tid == 255) rowptr[NN] = s[255];
}

__global__ __launch_bounds__(256) void k_fill(const int* __restrict__ src,
                                              const int* __restrict__ dst,
                                              const float* __restrict__ ew,
                                              const float* __restrict__ dinv,
                                              int* cur, int* col, float* val) {
    int e = blockIdx.x * 256 + threadIdx.x;
    if (e < NE) {
        int sN = src[e], d = dst[e];
        int pos = atomicAdd(&cur[d], 1);
        col[pos] = sN;
        val[pos] = dinv[sN] * ew[e] * dinv[d];
    }
}

// r1 = S * 1  (row sums of normalized adjacency incl self-loop)
__global__ __launch_bounds__(256) void k_rowsum(const int* __restrict__ rowptr,
                                                const float* __restrict__ val,
                                                const float* __restrict__ selfn,
                                                float* r1) {
    int n = blockIdx.x * 256 + threadIdx.x;
    if (n < NN) {
        float s = selfn[n];
        for (int p = rowptr[n]; p < rowptr[n + 1]; p++) s += val[p];
        r1[n] = s;
    }
}

// r2 = S * r1
__global__ __launch_bounds__(256) void k_r2(const int* __restrict__ rowptr,
                                            const int* __restrict__ col,
                                            const float* __restrict__ val,
                                            const float* __restrict__ selfn,
                                            const float* __restrict__ r1,
                                            float* r2) {
    int n = blockIdx.x * 256 + threadIdx.x;
    if (n < NN) {
        float s = selfn[n] * r1[n];
        for (int p = rowptr[n]; p < rowptr[n + 1]; p++)
            s += val[p] * r1[col[p]];
        r2[n] = s;
    }
}

// ---------------- weight folding ----------------
// W23 rows 0..127 = W2 @ W3 (128x64); row 128 = b2 @ W3 (d2)
__global__ __launch_bounds__(64) void k_w23(const float* __restrict__ W2,
                                            const float* __restrict__ b2,
                                            const float* __restrict__ W3,
                                            float* __restrict__ W23) {
    int i = blockIdx.x;        // 0..128
    int j = threadIdx.x;       // 0..63
    float acc = 0.f;
    if (i < H1C) {
        const float* row = W2 + (size_t)i * H2C;
        for (int k = 0; k < H2C; k++) acc += row[k] * W3[(size_t)k * COUT + j];
    } else {
        for (int k = 0; k < H2C; k++) acc += b2[k] * W3[(size_t)k * COUT + j];
    }
    W23[(size_t)i * COUT + j] = acc;
}

// W123d1 rows 0..31 = W1 @ W23[0:128] (32x64); row 32 = b1 @ W23[0:128] (d1)
__global__ __launch_bounds__(64) void k_w123(const float* __restrict__ W1,
                                             const float* __restrict__ b1,
                                             const float* __restrict__ W23,
                                             float* __restrict__ W123d1) {
    int i = blockIdx.x;        // 0..32
    int j = threadIdx.x;       // 0..63
    float acc = 0.f;
    if (i < CIN) {
        const float* row = W1 + (size_t)i * H1C;
        for (int k = 0; k < H1C; k++) acc += row[k] * W23[(size_t)k * COUT + j];
    } else {
        for (int k = 0; k < H1C; k++) acc += b1[k] * W23[(size_t)k * COUT + j];
    }
    W123d1[(size_t)i * COUT + j] = acc;
}

// ---------------- input transpose: x [B][CIN][T][N] -> xt [bt][n][CIN] ----------------
__global__ __launch_bounds__(256) void k_tin(const float* __restrict__ x,
                                             float* __restrict__ xt) {
    __shared__ float s[CIN][65];
    int tid = threadIdx.x;
    int bt = blockIdx.y, b = bt >> 3, t = bt & 7;
    int n0 = blockIdx.x * 64;
    const float* xp = x + ((size_t)b * CIN * TT + t) * NN;
    #pragma unroll
    for (int pass = 0; pass < 8; pass++) {
        int c = (tid >> 6) + pass * 4;
        int n = n0 + (tid & 63);
        s[c][tid & 63] = (n < NN) ? xp[(size_t)c * TT * NN + n] : 0.f;
    }
    __syncthreads();
    #pragma unroll
    for (int pass = 0; pass < 8; pass++) {
        int nn = (tid >> 5) + pass * 8;
        int n = n0 + nn;
        if (n < NN) xt[((size_t)bt * NN + n) * CIN + (tid & 31)] = s[tid & 31][nn];
    }
}

// ---------------- node-major 32-ch gather: out_row[n] = selfn[n]*in_row[n] + sum val*in_row[col] ----------------
__global__ __launch_bounds__(256) void k_gather32(
    const float* __restrict__ in, float* __restrict__ out,
    const int* __restrict__ rowptr, const int* __restrict__ col,
    const float* __restrict__ val, const float* __restrict__ selfn)
{
    int tid = threadIdx.x;
    int lane = tid & 63, wid = tid >> 6;
    int n = blockIdx.x * 4 + wid;
    int bt = blockIdx.y;
    int c = lane & 31, half = lane >> 5;
    const float* ip = in + (size_t)bt * NN * CIN;
    int p0 = rowptr[n], p1 = rowptr[n + 1];
    float acc = half ? 0.f : selfn[n] * ip[(size_t)n * CIN + c];
    for (int p = p0 + half; p < p1; p += 2)
        acc += val[p] * ip[(size_t)col[p] * CIN + c];
    acc += __shfl_xor(acc, 32);
    if (half == 0) out[((size_t)bt * NN + n) * CIN + c] = acc;
}

// ---------------- fused output: P = C3@W123 + r2*d1 + r1*d2 + b3; out = relu(P) transposed ----------------
__global__ __launch_bounds__(256) void k_out(
    const float* __restrict__ C3,       // [bt][n][32]
    const float* __restrict__ W123d1,   // 33x64 (row 32 = d1)
    const float* __restrict__ W23,      // row 128 = d2
    const float* __restrict__ b3,
    const float* __restrict__ r1, const float* __restrict__ r2,
    float* __restrict__ out)            // [B][COUT][T][N]
{
    __shared__ float Cs[64][32];
    __shared__ float Ws[32][64];
    __shared__ float Os[64][65];
    __shared__ float d1s[64], d2s[64], b3s[64], r1s[64], r2s[64];
    int tid = threadIdx.x;
    int bt = blockIdx.y, b = bt >> 3, t = bt & 7;
    int n0 = blockIdx.x * 64;
    int nvalid = NN - n0; if (nvalid > 64) nvalid = 64;

    const float* cp = C3 + ((size_t)bt * NN + n0) * CIN;
    for (int i = tid; i < 64 * CIN; i += 256) {
        int nn = i >> 5;
        Cs[nn][i & 31] = (nn < nvalid) ? cp[i] : 0.f;
    }
    for (int i = tid; i < CIN * 64; i += 256)
        Ws[i >> 6][i & 63] = W123d1[i];
    if (tid < 64) {
        d1s[tid] = W123d1[32 * 64 + tid];
        d2s[tid] = W23[128 * 64 + tid];
        b3s[tid] = b3[tid];
        int n = n0 + tid;
        r1s[tid] = (n < NN) ? r1[n] : 0.f;
        r2s[tid] = (n < NN) ? r2[n] : 0.f;
    }
    __syncthreads();

    int c = tid & 63, g = tid >> 6;
    for (int i = 0; i < 16; i++) {
        int nn = g * 16 + i;
        float acc = r2s[nn] * d1s[c] + r1s[nn] * d2s[c] + b3s[c];
        #pragma unroll
        for (int k = 0; k < CIN; k++) acc += Cs[nn][k] * Ws[k][c];
        Os[nn][c] = fmaxf(acc, 0.f);
    }
    __syncthreads();

    #pragma unroll
    for (int pass = 0; pass < 16; pass++) {
        int cc = g + pass * 4;
        int n = n0 + (tid & 63);
        if (n < NN)
            out[(((size_t)b * COUT + cc) * TT + t) * NN + n] = Os[tid & 63][cc];
    }
}

// ---------------- launch ----------------

extern "C" void kernel_launch(void* const* d_in, const int* in_sizes, int n_in,
                              void* d_out, int out_size, void* d_ws, size_t ws_size,
                              hipStream_t stream) {
    (void)in_sizes; (void)n_in; (void)out_size; (void)ws_size;

    const float* x  = (const float*)d_in[0];
    const int*   ei = (const int*)d_in[1];
    const float* ew = (const float*)d_in[2];
    const float* W1 = (const float*)d_in[3];
    const float* b1 = (const float*)d_in[4];
    const float* W2 = (const float*)d_in[5];
    const float* b2 = (const float*)d_in[6];
    const float* W3 = (const float*)d_in[7];
    const float* b3 = (const float*)d_in[8];
    float* out = (float*)d_out;

    const int* src = ei;
    const int* dst = ei + NE;

    // workspace layout (float offsets)
    float* ws     = (float*)d_ws;
    float* deg    = ws;                        // 2048
    float* dinv   = ws + 2048;                 // 2048
    float* selfn  = ws + 4096;                 // 2048
    float* val    = ws + 6144;                 // NE
    float* r1     = ws + 6144 + NE;            // 2048
    float* r2     = r1 + 2048;                 // 2048
    float* W23    = r2 + 2048;                 // 129*64 = 8256
    float* W123d1 = W23 + 8256;                // 33*64 = 2112
    int*   cnt    = (int*)(W123d1 + 2112);     // 2048
    int*   cur    = cnt + 2048;                // 2048
    int*   rowptr = cur + 2048;                // 2048 (NN+1 used)
    int*   col    = rowptr + 2048;             // NE
    float* xt     = (float*)(col + NE) + 16;   // 2.048M floats each below
    // align to 16 floats
    xt = (float*)(((uintptr_t)xt + 63) & ~(uintptr_t)63);
    float* A   = xt + (size_t)BT * NN * CIN;
    float* Bb  = A  + (size_t)BT * NN * CIN;
    float* C3  = Bb + (size_t)BT * NN * CIN;

    // prep CSR + norms
    k_init <<<dim3(8), dim3(256), 0, stream>>>(deg, cnt);
    k_count<<<dim3((NE + 255) / 256), dim3(256), 0, stream>>>(dst, ew, deg, cnt);
    k_dinv <<<dim3(8), dim3(256), 0, stream>>>(deg, dinv, selfn);
    k_scan <<<dim3(1), dim3(256), 0, stream>>>(cnt, rowptr, cur);
    k_fill <<<dim3((NE + 255) / 256), dim3(256), 0, stream>>>(src, dst, ew, dinv, cur, col, val);

    // row sums r1 = S*1, r2 = S*r1
    k_rowsum<<<dim3(8), dim3(256), 0, stream>>>(rowptr, val, selfn, r1);
    k_r2    <<<dim3(8), dim3(256), 0, stream>>>(rowptr, col, val, selfn, r1, r2);

    // weight folding: W23 (incl d2 row), W123d1 (incl d1 row)
    k_w23 <<<dim3(129), dim3(64), 0, stream>>>(W2, b2, W3, W23);
    k_w123<<<dim3(33),  dim3(64), 0, stream>>>(W1, b1, W23, W123d1);

    // input transpose -> node-major xt [bt][n][32]
    k_tin<<<dim3(32, BT), dim3(256), 0, stream>>>(x, xt);

    // S^3 * X  (three 32-channel gathers)
    k_gather32<<<dim3(NN / 4, BT), dim3(256), 0, stream>>>(xt, A,  rowptr, col, val, selfn);
    k_gather32<<<dim3(NN / 4, BT), dim3(256), 0, stream>>>(A,  Bb, rowptr, col, val, selfn);
    k_gather32<<<dim3(NN / 4, BT), dim3(256), 0, stream>>>(Bb, C3, rowptr, col, val, selfn);

    // fused: (S^3 X) @ W123 + rank-1 bias corrections + relu + transposed store
    k_out<<<dim3((NN + 63) / 64, BT), dim3(256), 0, stream>>>(
        C3, W123d1, W23, b3, r1, r2, out);
}

// Round 4
// 137.303 us; speedup vs baseline: 4.0987x; 1.1629x over previous
//
#include <hip/hip_runtime.h>
#include <hip/hip_bf16.h>

// Problem constants (from reference)
#define NB 4       // batch
#define CIN 32
#define TT 8       // time steps
#define NN 2000    // nodes
#define NE 16000   // edges
#define H1C 128
#define H2C 256
#define COUT 64
#define BT (NB*TT) // 32 graph replicas

// =============== kernel 1: prep (block 0 = CSR + r1/r2, blocks 1..8 = weight folding) ===============
__global__ __launch_bounds__(1024) void k_prep(
    const int* __restrict__ src, const int* __restrict__ dst,
    const float* __restrict__ ew,
    const float* __restrict__ W1, const float* __restrict__ b1,
    const float* __restrict__ W2, const float* __restrict__ b2,
    const float* __restrict__ W3,
    int* __restrict__ rowptr_g, int* __restrict__ col_g, float* __restrict__ val_g,
    float* __restrict__ selfn_g, float* __restrict__ r1_g, float* __restrict__ r2_g,
    float* __restrict__ W123_g, float* __restrict__ d1_g, float* __restrict__ d2_g)
{
    const int tid = threadIdx.x;

    if (blockIdx.x == 0) {
        // ---------- CSR + norms + r1/r2, entirely within one block ----------
        __shared__ float degs[NN];
        __shared__ float dinvs[NN];
        __shared__ float r1s[NN];
        __shared__ float r2s[NN];
        __shared__ int   cnts[NN];
        __shared__ int   rps[NN + 1];
        __shared__ int   curs[NN];
        __shared__ int   sscan[256];

        for (int i = tid; i < NN; i += 1024) {
            degs[i] = 1.0f;   // self-loop
            cnts[i] = 0;
            r1s[i] = 0.0f;
            r2s[i] = 0.0f;
        }
        __syncthreads();

        for (int e = tid; e < NE; e += 1024) {
            int d = dst[e];
            atomicAdd(&degs[d], ew[e]);
            atomicAdd(&cnts[d], 1);
        }
        __syncthreads();

        for (int i = tid; i < NN; i += 1024) {
            float di = 1.0f / sqrtf(degs[i]);
            dinvs[i] = di;
            selfn_g[i] = di * di;
        }
        __syncthreads();

        // exclusive scan of cnts (threads 0..255, 8 elems each)
        int local[8];
        int chunk_excl = 0;
        if (tid < 256) {
            int base = tid * 8, sum = 0;
            #pragma unroll
            for (int i = 0; i < 8; i++) {
                int idx = base + i;
                int v = (idx < NN) ? cnts[idx] : 0;
                local[i] = sum;
                sum += v;
            }
            sscan[tid] = sum;
        }
        __syncthreads();
        for (int off = 1; off < 256; off <<= 1) {
            int v = 0;
            if (tid < 256 && tid >= off) v = sscan[tid - off];
            __syncthreads();
            if (tid < 256 && tid >= off) sscan[tid] += v;
            __syncthreads();
        }
        if (tid < 256) {
            chunk_excl = (tid > 0) ? sscan[tid - 1] : 0;
            int base = tid * 8;
            #pragma unroll
            for (int i = 0; i < 8; i++) {
                int idx = base + i;
                if (idx < NN) {
                    int rp = chunk_excl + local[i];
                    rps[idx] = rp;
                    curs[idx] = rp;
                }
            }
            if (tid == 255) rps[NN] = sscan[255];
        }
        __syncthreads();

        // fill CSR (dst-sorted) + accumulate edge part of r1
        for (int e = tid; e < NE; e += 1024) {
            int s = src[e], d = dst[e];
            int pos = atomicAdd(&curs[d], 1);
            float v = dinvs[s] * ew[e] * dinvs[d];
            col_g[pos] = s;
            val_g[pos] = v;
            atomicAdd(&r1s[d], v);
        }
        __syncthreads();

        // finalize r1 = selfn + edge sum
        for (int i = tid; i < NN; i += 1024)
            r1s[i] += dinvs[i] * dinvs[i];
        __syncthreads();

        // r2 = S * r1 (edge-parallel, recompute v from LDS inputs)
        for (int e = tid; e < NE; e += 1024) {
            int s = src[e], d = dst[e];
            float v = dinvs[s] * ew[e] * dinvs[d];
            atomicAdd(&r2s[d], v * r1s[s]);
        }
        __syncthreads();

        for (int i = tid; i < NN; i += 1024) {
            float sn = dinvs[i] * dinvs[i];
            r1_g[i] = r1s[i];
            r2_g[i] = r2s[i] + sn * r1s[i];
            rowptr_g[i] = rps[i];
        }
        if (tid == 0) rowptr_g[NN] = rps[NN];
    } else {
        // ---------- weight folding, 8-column slice per block ----------
        __shared__ float W3s[H2C][8];       // 8KB
        __shared__ float W23s[H1C + 1][8];  // rows 0..127 = W2@W3 slice, row 128 = b2@W3
        const int j0 = (blockIdx.x - 1) * 8;

        for (int i = tid; i < H2C * 8; i += 1024)
            W3s[i >> 3][i & 7] = W3[(size_t)(i >> 3) * COUT + j0 + (i & 7)];
        __syncthreads();

        for (int r = tid >> 3; r < H1C + 1; r += 128) {
            int j = tid & 7;
            const float* wrow = (r < H1C) ? (W2 + (size_t)r * H2C) : b2;
            float acc = 0.f;
            for (int k = 0; k < H2C; k++) acc += wrow[k] * W3s[k][j];
            W23s[r][j] = acc;
        }
        __syncthreads();

        for (int r = tid >> 3; r < CIN + 1; r += 128) {
            int j = tid & 7;
            const float* wrow = (r < CIN) ? (W1 + (size_t)r * H1C) : b1;
            float acc = 0.f;
            for (int k = 0; k < H1C; k++) acc += wrow[k] * W23s[k][j];
            if (r < CIN) W123_g[(size_t)r * COUT + j0 + j] = acc;
            else         d1_g[j0 + j] = acc;
        }
        if (tid < 8) d2_g[j0 + tid] = W23s[H1C][tid];
    }
}

// =============== kernel 2: fused S^3 * X per (channel-group, bt), all in LDS ===============
// grid (8, 32): x = channel group (4 ch), y = bt. 1024 threads.
__global__ __launch_bounds__(1024) void k_sss(
    const float* __restrict__ x,
    const int* __restrict__ rowptr_g, const int* __restrict__ col,
    const float* __restrict__ val, const float* __restrict__ selfn_g,
    float* __restrict__ C3)     // [bt][32][2000] channel-major
{
    __shared__ float bufA[4][2049];
    __shared__ float bufB[4][2049];
    __shared__ float selfns[NN];
    __shared__ int   rps[NN + 1];

    const int tid = threadIdx.x;
    const int cg = blockIdx.x, bt = blockIdx.y;
    const int b = bt >> 3, t = bt & 7;

    for (int i = tid; i < NN; i += 1024) selfns[i] = selfn_g[i];
    for (int i = tid; i < NN + 1; i += 1024) rps[i] = rowptr_g[i];

    // load x slice coalesced: 4 channel rows of 2000 contiguous floats
    #pragma unroll
    for (int c = 0; c < 4; c++) {
        const float* xr = x + (((size_t)b * CIN + cg * 4 + c) * TT + t) * NN;
        for (int i = tid; i < NN; i += 1024) bufA[c][i] = xr[i];
    }
    __syncthreads();

    const int c = tid & 3, nq = tid >> 2;   // 256 node-groups x 4 channels

    auto do_gather = [&](const float* S, float* D) {
        const float* Sc = S + c * 2049;
        float* Dc = D + c * 2049;
        for (int n = nq; n < NN; n += 256) {
            int p0 = rps[n], p1 = rps[n + 1];
            float acc = selfns[n] * Sc[n];
            int p = p0;
            for (; p + 1 < p1; p += 2) {
                int s0 = col[p], s1 = col[p + 1];
                float v0 = val[p], v1 = val[p + 1];
                acc += v0 * Sc[s0] + v1 * Sc[s1];
            }
            if (p < p1) acc += val[p] * Sc[col[p]];
            Dc[n] = acc;
        }
    };

    do_gather(&bufA[0][0], &bufB[0][0]); __syncthreads();
    do_gather(&bufB[0][0], &bufA[0][0]); __syncthreads();
    do_gather(&bufA[0][0], &bufB[0][0]); __syncthreads();

    // store channel-major C3[bt][ch][n]
    #pragma unroll
    for (int cc = 0; cc < 4; cc++) {
        float* orow = C3 + ((size_t)bt * CIN + cg * 4 + cc) * NN;
        for (int i = tid; i < NN; i += 1024) orow[i] = bufB[cc][i];
    }
}

// =============== kernel 3: P = C3@W123 + r2*d1 + r1*d2 + b3; out = relu(P), transposed store ===============
__global__ __launch_bounds__(256) void k_out(
    const float* __restrict__ C3,       // [bt][32][2000]
    const float* __restrict__ W123,     // 32x64
    const float* __restrict__ d1, const float* __restrict__ d2,
    const float* __restrict__ b3,
    const float* __restrict__ r1, const float* __restrict__ r2,
    float* __restrict__ out)            // [B][COUT][T][N]
{
    __shared__ float Cs[CIN][65];
    __shared__ float Ws[CIN][64];
    __shared__ float Os[64][65];
    __shared__ float d1s[64], d2s[64], b3s[64], r1s[64], r2s[64];
    const int tid = threadIdx.x;
    const int bt = blockIdx.y, b = bt >> 3, t = bt & 7;
    const int n0 = blockIdx.x * 64;

    for (int i = tid; i < CIN * 64; i += 256) {
        int ch = i >> 6, nn = i & 63;
        int n = n0 + nn;
        Cs[ch][nn] = (n < NN) ? C3[((size_t)bt * CIN + ch) * NN + n] : 0.f;
    }
    for (int i = tid; i < CIN * 64; i += 256)
        Ws[i >> 6][i & 63] = W123[i];
    if (tid < 64) {
        d1s[tid] = d1[tid];
        d2s[tid] = d2[tid];
        b3s[tid] = b3[tid];
        int n = n0 + tid;
        r1s[tid] = (n < NN) ? r1[n] : 0.f;
        r2s[tid] = (n < NN) ? r2[n] : 0.f;
    }
    __syncthreads();

    const int c = tid & 63, g = tid >> 6;
    for (int i = 0; i < 16; i++) {
        int nn = g * 16 + i;
        float acc = r2s[nn] * d1s[c] + r1s[nn] * d2s[c] + b3s[c];
        #pragma unroll
        for (int k = 0; k < CIN; k++) acc += Cs[k][nn] * Ws[k][c];
        Os[nn][c] = fmaxf(acc, 0.f);
    }
    __syncthreads();

    #pragma unroll
    for (int pass = 0; pass < 16; pass++) {
        int cc = g + pass * 4;
        int n = n0 + (tid & 63);
        if (n < NN)
            out[(((size_t)b * COUT + cc) * TT + t) * NN + n] = Os[tid & 63][cc];
    }
}

// ---------------- launch ----------------

extern "C" void kernel_launch(void* const* d_in, const int* in_sizes, int n_in,
                              void* d_out, int out_size, void* d_ws, size_t ws_size,
                              hipStream_t stream) {
    (void)in_sizes; (void)n_in; (void)out_size; (void)ws_size;

    const float* x  = (const float*)d_in[0];
    const int*   ei = (const int*)d_in[1];
    const float* ew = (const float*)d_in[2];
    const float* W1 = (const float*)d_in[3];
    const float* b1 = (const float*)d_in[4];
    const float* W2 = (const float*)d_in[5];
    const float* b2 = (const float*)d_in[6];
    const float* W3 = (const float*)d_in[7];
    const float* b3 = (const float*)d_in[8];
    float* out = (float*)d_out;

    const int* src = ei;
    const int* dst = ei + NE;

    // workspace layout (float units)
    float* ws     = (float*)d_ws;
    int*   rowptr = (int*)ws;                  // 2048
    int*   col    = rowptr + 2048;             // NE
    float* val    = (float*)(col + NE);        // NE
    float* selfn  = val + NE;                  // 2048
    float* r1     = selfn + 2048;              // 2048
    float* r2     = r1 + 2048;                 // 2048
    float* W123   = r2 + 2048;                 // 2048
    float* d1     = W123 + 2048;               // 64
    float* d2     = d1 + 64;                   // 64
    float* C3     = d2 + 64 + 64;              // 32*32*2000

    k_prep<<<dim3(9), dim3(1024), 0, stream>>>(
        src, dst, ew, W1, b1, W2, b2, W3,
        rowptr, col, val, selfn, r1, r2, W123, d1, d2);

    k_sss<<<dim3(8, BT), dim3(1024), 0, stream>>>(
        x, rowptr, col, val, selfn, C3);

    k_out<<<dim3(32, BT), dim3(256), 0, stream>>>(
        C3, W123, d1, d2, b3, r1, r2, out);
}

// Round 5
// 125.738 us; speedup vs baseline: 4.4757x; 1.0920x over previous
//
#include <hip/hip_runtime.h>
#include <hip/hip_bf16.h>

// Problem constants (from reference)
#define NB 4       // batch
#define CIN 32
#define TT 8       // time steps
#define NN 2000    // nodes
#define NE 16000   // edges
#define H1C 128
#define H2C 256
#define COUT 64
#define BT (NB*TT) // 32 graph replicas

// =============== kernel 1: prep (block 0 = CSR + r1/r2, blocks 1..8 = weight folding) ===============
// No float atomics anywhere: int atomics for counting/slot assignment, then
// node-parallel conflict-free CSR reductions for deg/dinv/val/r1/r2.
__global__ __launch_bounds__(1024) void k_prep(
    const int* __restrict__ src, const int* __restrict__ dst,
    const float* __restrict__ ew,
    const float* __restrict__ W1, const float* __restrict__ b1,
    const float* __restrict__ W2, const float* __restrict__ b2,
    const float* __restrict__ W3,
    int* __restrict__ rowptr_g, int* __restrict__ col_g,
    float* __restrict__ ewr_g, float* __restrict__ val_g,
    float* __restrict__ selfn_g, float* __restrict__ r1_g, float* __restrict__ r2_g,
    float* __restrict__ W123_g, float* __restrict__ d1_g, float* __restrict__ d2_g)
{
    const int tid = threadIdx.x;

    if (blockIdx.x == 0) {
        __shared__ int   cnts[NN];
        __shared__ int   rps[NN + 1];
        __shared__ int   curs[NN];
        __shared__ float dinvs[NN];
        __shared__ float r1s[NN];
        __shared__ int   sscan[256];

        for (int i = tid; i < NN; i += 1024) cnts[i] = 0;
        __syncthreads();

        // pass A: per-dst edge counts (native int LDS atomics)
        for (int e = tid; e < NE; e += 1024)
            atomicAdd(&cnts[dst[e]], 1);
        __syncthreads();

        // exclusive scan of cnts (threads 0..255, 8 elems each)
        int local[8];
        if (tid < 256) {
            int base = tid * 8, sum = 0;
            #pragma unroll
            for (int i = 0; i < 8; i++) {
                int idx = base + i;
                int v = (idx < NN) ? cnts[idx] : 0;
                local[i] = sum;
                sum += v;
            }
            sscan[tid] = sum;
        }
        __syncthreads();
        for (int off = 1; off < 256; off <<= 1) {
            int v = 0;
            if (tid < 256 && tid >= off) v = sscan[tid - off];
            __syncthreads();
            if (tid < 256 && tid >= off) sscan[tid] += v;
            __syncthreads();
        }
        if (tid < 256) {
            int chunk_excl = (tid > 0) ? sscan[tid - 1] : 0;
            int base = tid * 8;
            #pragma unroll
            for (int i = 0; i < 8; i++) {
                int idx = base + i;
                if (idx < NN) {
                    int rp = chunk_excl + local[i];
                    rps[idx] = rp;
                    curs[idx] = rp;
                }
            }
            if (tid == 255) rps[NN] = sscan[255];
        }
        __syncthreads();

        // pass B: fill dst-sorted CSR with src index and raw edge weight
        for (int e = tid; e < NE; e += 1024) {
            int d = dst[e];
            int pos = atomicAdd(&curs[d], 1);   // native int LDS atomic
            col_g[pos] = src[e];
            ewr_g[pos] = ew[e];
        }
        __syncthreads();   // drains global writes; same-block RAW is safe after barrier

        // node-parallel: deg -> dinv, selfn, export rowptr
        for (int n = tid; n < NN; n += 1024) {
            float s = 1.0f;   // self-loop
            int p0 = rps[n], p1 = rps[n + 1];
            for (int p = p0; p < p1; p++) s += ewr_g[p];
            float di = 1.0f / sqrtf(s);
            dinvs[n] = di;
            selfn_g[n] = di * di;
            rowptr_g[n] = p0;
        }
        if (tid == 0) rowptr_g[NN] = rps[NN];
        __syncthreads();

        // node-parallel: val[p] and r1 = S*1
        for (int n = tid; n < NN; n += 1024) {
            float di = dinvs[n];
            float acc = di * di;
            int p0 = rps[n], p1 = rps[n + 1];
            for (int p = p0; p < p1; p++) {
                float v = dinvs[col_g[p]] * ewr_g[p] * di;
                val_g[p] = v;
                acc += v;
            }
            r1s[n] = acc;
            r1_g[n] = acc;
        }
        __syncthreads();

        // node-parallel: r2 = S*r1
        for (int n = tid; n < NN; n += 1024) {
            float di = dinvs[n];
            float acc = di * di * r1s[n];
            int p0 = rps[n], p1 = rps[n + 1];
            for (int p = p0; p < p1; p++)
                acc += val_g[p] * r1s[col_g[p]];
            r2_g[n] = acc;
        }
    } else {
        // ---------- weight folding, 8-column slice per block ----------
        __shared__ float W3s[H2C][8];       // 8KB
        __shared__ float W23s[H1C + 1][8];  // rows 0..127 = W2@W3 slice, row 128 = b2@W3
        const int j0 = (blockIdx.x - 1) * 8;

        for (int i = tid; i < H2C * 8; i += 1024)
            W3s[i >> 3][i & 7] = W3[(size_t)(i >> 3) * COUT + j0 + (i & 7)];
        __syncthreads();

        for (int r = tid >> 3; r < H1C + 1; r += 128) {
            int j = tid & 7;
            const float* wrow = (r < H1C) ? (W2 + (size_t)r * H2C) : b2;
            float acc = 0.f;
            for (int k = 0; k < H2C; k++) acc += wrow[k] * W3s[k][j];
            W23s[r][j] = acc;
        }
        __syncthreads();

        for (int r = tid >> 3; r < CIN + 1; r += 128) {
            int j = tid & 7;
            const float* wrow = (r < CIN) ? (W1 + (size_t)r * H1C) : b1;
            float acc = 0.f;
            for (int k = 0; k < H1C; k++) acc += wrow[k] * W23s[k][j];
            if (r < CIN) W123_g[(size_t)r * COUT + j0 + j] = acc;
            else         d1_g[j0 + j] = acc;
        }
        if (tid < 8) d2_g[j0 + tid] = W23s[H1C][tid];
    }
}

// =============== kernel 2: fused S^3 * X per (channel-group, bt), all in LDS ===============
// grid (8, 32): x = channel group (4 ch), y = bt. 1024 threads.
__global__ __launch_bounds__(1024) void k_sss(
    const float* __restrict__ x,
    const int* __restrict__ rowptr_g, const int* __restrict__ col,
    const float* __restrict__ val, const float* __restrict__ selfn_g,
    float* __restrict__ C3)     // [bt][32][2000] channel-major
{
    __shared__ float bufA[4][2049];
    __shared__ float bufB[4][2049];
    __shared__ float selfns[NN];
    __shared__ int   rps[NN + 1];

    const int tid = threadIdx.x;
    const int cg = blockIdx.x, bt = blockIdx.y;
    const int b = bt >> 3, t = bt & 7;

    for (int i = tid; i < NN; i += 1024) selfns[i] = selfn_g[i];
    for (int i = tid; i < NN + 1; i += 1024) rps[i] = rowptr_g[i];

    // load x slice coalesced: 4 channel rows of 2000 contiguous floats
    #pragma unroll
    for (int c = 0; c < 4; c++) {
        const float* xr = x + (((size_t)b * CIN + cg * 4 + c) * TT + t) * NN;
        for (int i = tid; i < NN; i += 1024) bufA[c][i] = xr[i];
    }
    __syncthreads();

    const int c = tid & 3, nq = tid >> 2;   // 256 node-groups x 4 channels

    auto do_gather = [&](const float* S, float* D) {
        const float* Sc = S + c * 2049;
        float* Dc = D + c * 2049;
        for (int n = nq; n < NN; n += 256) {
            int p0 = rps[n], p1 = rps[n + 1];
            float acc = selfns[n] * Sc[n];
            int p = p0;
            for (; p + 1 < p1; p += 2) {
                int s0 = col[p], s1 = col[p + 1];
                float v0 = val[p], v1 = val[p + 1];
                acc += v0 * Sc[s0] + v1 * Sc[s1];
            }
            if (p < p1) acc += val[p] * Sc[col[p]];
            Dc[n] = acc;
        }
    };

    do_gather(&bufA[0][0], &bufB[0][0]); __syncthreads();
    do_gather(&bufB[0][0], &bufA[0][0]); __syncthreads();
    do_gather(&bufA[0][0], &bufB[0][0]); __syncthreads();

    // store channel-major C3[bt][ch][n]
    #pragma unroll
    for (int cc = 0; cc < 4; cc++) {
        float* orow = C3 + ((size_t)bt * CIN + cg * 4 + cc) * NN;
        for (int i = tid; i < NN; i += 1024) orow[i] = bufB[cc][i];
    }
}

// =============== kernel 3: P = C3@W123 + r2*d1 + r1*d2 + b3; out = relu(P), transposed store ===============
__global__ __launch_bounds__(256) void k_out(
    const float* __restrict__ C3,       // [bt][32][2000]
    const float* __restrict__ W123,     // 32x64
    const float* __restrict__ d1, const float* __restrict__ d2,
    const float* __restrict__ b3,
    const float* __restrict__ r1, const float* __restrict__ r2,
    float* __restrict__ out)            // [B][COUT][T][N]
{
    __shared__ float Cs[CIN][65];
    __shared__ float Ws[CIN][64];
    __shared__ float Os[64][65];
    __shared__ float d1s[64], d2s[64], b3s[64], r1s[64], r2s[64];
    const int tid = threadIdx.x;
    const int bt = blockIdx.y, b = bt >> 3, t = bt & 7;
    const int n0 = blockIdx.x * 64;

    for (int i = tid; i < CIN * 64; i += 256) {
        int ch = i >> 6, nn = i & 63;
        int n = n0 + nn;
        Cs[ch][nn] = (n < NN) ? C3[((size_t)bt * CIN + ch) * NN + n] : 0.f;
    }
    for (int i = tid; i < CIN * 64; i += 256)
        Ws[i >> 6][i & 63] = W123[i];
    if (tid < 64) {
        d1s[tid] = d1[tid];
        d2s[tid] = d2[tid];
        b3s[tid] = b3[tid];
        int n = n0 + tid;
        r1s[tid] = (n < NN) ? r1[n] : 0.f;
        r2s[tid] = (n < NN) ? r2[n] : 0.f;
    }
    __syncthreads();

    const int c = tid & 63, g = tid >> 6;
    for (int i = 0; i < 16; i++) {
        int nn = g * 16 + i;
        float acc = r2s[nn] * d1s[c] + r1s[nn] * d2s[c] + b3s[c];
        #pragma unroll
        for (int k = 0; k < CIN; k++) acc += Cs[k][nn] * Ws[k][c];
        Os[nn][c] = fmaxf(acc, 0.f);
    }
    __syncthreads();

    #pragma unroll
    for (int pass = 0; pass < 16; pass++) {
        int cc = g + pass * 4;
        int n = n0 + (tid & 63);
        if (n < NN)
            out[(((size_t)b * COUT + cc) * TT + t) * NN + n] = Os[tid & 63][cc];
    }
}

// ---------------- launch ----------------

extern "C" void kernel_launch(void* const* d_in, const int* in_sizes, int n_in,
                              void* d_out, int out_size, void* d_ws, size_t ws_size,
                              hipStream_t stream) {
    (void)in_sizes; (void)n_in; (void)out_size; (void)ws_size;

    const float* x  = (const float*)d_in[0];
    const int*   ei = (const int*)d_in[1];
    const float* ew = (const float*)d_in[2];
    const float* W1 = (const float*)d_in[3];
    const float* b1 = (const float*)d_in[4];
    const float* W2 = (const float*)d_in[5];
    const float* b2 = (const float*)d_in[6];
    const float* W3 = (const float*)d_in[7];
    const float* b3 = (const float*)d_in[8];
    float* out = (float*)d_out;

    const int* src = ei;
    const int* dst = ei + NE;

    // workspace layout (float units)
    float* ws     = (float*)d_ws;
    int*   rowptr = (int*)ws;                  // 2048
    int*   col    = rowptr + 2048;             // NE
    float* ewr    = (float*)(col + NE);        // NE (CSR-ordered raw edge weights)
    float* val    = ewr + NE;                  // NE
    float* selfn  = val + NE;                  // 2048
    float* r1     = selfn + 2048;              // 2048
    float* r2     = r1 + 2048;                 // 2048
    float* W123   = r2 + 2048;                 // 2048
    float* d1     = W123 + 2048;               // 64
    float* d2     = d1 + 64;                   // 64
    float* C3     = d2 + 64 + 64;              // 32*32*2000

    k_prep<<<dim3(9), dim3(1024), 0, stream>>>(
        src, dst, ew, W1, b1, W2, b2, W3,
        rowptr, col, ewr, val, selfn, r1, r2, W123, d1, d2);

    k_sss<<<dim3(8, BT), dim3(1024), 0, stream>>>(
        x, rowptr, col, val, selfn, C3);

    k_out<<<dim3(32, BT), dim3(256), 0, stream>>>(
        C3, W123, d1, d2, b3, r1, r2, out);
}

// Round 6
// 109.469 us; speedup vs baseline: 5.1408x; 1.1486x over previous
//
#include <hip/hip_runtime.h>
#include <hip/hip_bf16.h>

// Problem constants (from reference)
#define NB 4       // batch
#define CIN 32
#define TT 8       // time steps
#define NN 2000    // nodes
#define NE 16000   // edges
#define H1C 128
#define H2C 256
#define COUT 64
#define BT (NB*TT) // 32 graph replicas

// =============== kernel 1: blocks 0..7 weight folding, blocks 8..71 edge count ===============
__global__ __launch_bounds__(256) void k_count(
    const int* __restrict__ src, const int* __restrict__ dst,
    const float* __restrict__ ew,
    const float* __restrict__ W1, const float* __restrict__ b1,
    const float* __restrict__ W2, const float* __restrict__ b2,
    const float* __restrict__ W3,
    int* __restrict__ cnt, float* __restrict__ deg,
    float* __restrict__ W123_g, float* __restrict__ d1_g, float* __restrict__ d2_g)
{
    const int tid = threadIdx.x;
    (void)src;

    if (blockIdx.x < 8) {
        // ---------- weight folding, 8-column slice per block ----------
        __shared__ float W3s[H2C][8];       // 8KB
        __shared__ float W23s[H1C + 1][8];  // rows 0..127 = W2@W3 slice, row 128 = b2@W3
        const int j0 = blockIdx.x * 8;

        for (int i = tid; i < H2C * 8; i += 256)
            W3s[i >> 3][i & 7] = W3[(size_t)(i >> 3) * COUT + j0 + (i & 7)];
        __syncthreads();

        for (int r = tid >> 3; r < H1C + 1; r += 32) {
            int j = tid & 7;
            const float* wrow = (r < H1C) ? (W2 + (size_t)r * H2C) : b2;
            float acc = 0.f;
            for (int k = 0; k < H2C; k++) acc += wrow[k] * W3s[k][j];
            W23s[r][j] = acc;
        }
        __syncthreads();

        for (int r = tid >> 3; r < CIN + 1; r += 32) {
            int j = tid & 7;
            const float* wrow = (r < CIN) ? (W1 + (size_t)r * H1C) : b1;
            float acc = 0.f;
            for (int k = 0; k < H1C; k++) acc += wrow[k] * W23s[k][j];
            if (r < CIN) W123_g[(size_t)r * COUT + j0 + j] = acc;
            else         d1_g[j0 + j] = acc;
        }
        if (tid < 8) d2_g[j0 + tid] = W23s[H1C][tid];
    } else {
        int e = (blockIdx.x - 8) * 256 + tid;
        if (e < NE) {
            int d = dst[e];
            atomicAdd(&cnt[d], 1);
            atomicAdd(&deg[d], ew[e]);   // native global float atomic
        }
    }
}

// =============== kernel 2: single small block: scan + dinv/selfn ===============
__global__ __launch_bounds__(256) void k_scan(
    const int* __restrict__ cnt, const float* __restrict__ deg,
    int* __restrict__ rowptr, int* __restrict__ cur,
    float* __restrict__ dinv, float* __restrict__ selfn)
{
    __shared__ int sscan[256];
    const int tid = threadIdx.x;
    int local[8];
    int base = tid * 8, sum = 0;
    #pragma unroll
    for (int i = 0; i < 8; i++) {
        int idx = base + i;
        int v = (idx < NN) ? cnt[idx] : 0;
        local[i] = sum;
        sum += v;
    }
    sscan[tid] = sum;
    __syncthreads();
    for (int off = 1; off < 256; off <<= 1) {
        int v = 0;
        if (tid >= off) v = sscan[tid - off];
        __syncthreads();
        if (tid >= off) sscan[tid] += v;
        __syncthreads();
    }
    int chunk_excl = (tid > 0) ? sscan[tid - 1] : 0;
    #pragma unroll
    for (int i = 0; i < 8; i++) {
        int idx = base + i;
        if (idx < NN) {
            int rp = chunk_excl + local[i];
            rowptr[idx] = rp;
            cur[idx] = rp;
        }
    }
    if (tid == 255) rowptr[NN] = sscan[255];

    for (int n = tid; n < NN; n += 256) {
        float di = 1.0f / sqrtf(1.0f + deg[n]);   // deg holds edge-sum; +1 = self-loop
        dinv[n] = di;
        selfn[n] = di * di;
    }
}

// =============== kernel 3: CSR fill ===============
__global__ __launch_bounds__(256) void k_fill(
    const int* __restrict__ src, const int* __restrict__ dst,
    const float* __restrict__ ew, const float* __restrict__ dinv,
    int* __restrict__ cur, int* __restrict__ col, float* __restrict__ val)
{
    int e = blockIdx.x * 256 + threadIdx.x;
    if (e < NE) {
        int s = src[e], d = dst[e];
        int pos = atomicAdd(&cur[d], 1);
        col[pos] = s;
        val[pos] = dinv[s] * ew[e] * dinv[d];
    }
}

// =============== kernel 4: fused S^3 * X per (channel-group, bt), LDS ping-pong ===============
// grid (8, 32): x = channel group (4 ch), y = bt. 1024 threads.
// Block (0,0) additionally emits r1f = S*1 (overwrite => replay-safe).
__global__ __launch_bounds__(1024) void k_sss(
    const float* __restrict__ x,
    const int* __restrict__ rowptr_g, const int* __restrict__ col,
    const float* __restrict__ val, const float* __restrict__ selfn_g,
    float* __restrict__ r1f,
    float* __restrict__ C3)     // [bt][32][2000] channel-major
{
    __shared__ float bufA[4][2049];
    __shared__ float bufB[4][2049];

    const int tid = threadIdx.x;
    const int cg = blockIdx.x, bt = blockIdx.y;
    const int b = bt >> 3, t = bt & 7;

    // load x slice coalesced: 4 channel rows of 2000 contiguous floats
    #pragma unroll
    for (int c = 0; c < 4; c++) {
        const float* xr = x + (((size_t)b * CIN + cg * 4 + c) * TT + t) * NN;
        for (int i = tid; i < NN; i += 1024) bufA[c][i] = xr[i];
    }

    // side job: r1f = selfn + row-sum of val (only block (0,0))
    if (cg == 0 && bt == 0) {
        for (int n = tid; n < NN; n += 1024) {
            float acc = selfn_g[n];
            int p0 = rowptr_g[n], p1 = rowptr_g[n + 1];
            for (int p = p0; p < p1; p++) acc += val[p];
            r1f[n] = acc;
        }
    }
    __syncthreads();

    const int c = tid & 3, nq = tid >> 2;   // 256 node-groups x 4 channels

    auto do_gather = [&](const float* S, float* D) {
        const float* Sc = S + c * 2049;
        float* Dc = D + c * 2049;
        for (int n = nq; n < NN; n += 256) {
            int p0 = rowptr_g[n], p1 = rowptr_g[n + 1];
            float acc = selfn_g[n] * Sc[n];
            int p = p0;
            for (; p + 1 < p1; p += 2) {
                int s0 = col[p], s1 = col[p + 1];
                float v0 = val[p], v1 = val[p + 1];
                acc += v0 * Sc[s0] + v1 * Sc[s1];
            }
            if (p < p1) acc += val[p] * Sc[col[p]];
            Dc[n] = acc;
        }
    };

    do_gather(&bufA[0][0], &bufB[0][0]); __syncthreads();
    do_gather(&bufB[0][0], &bufA[0][0]); __syncthreads();
    do_gather(&bufA[0][0], &bufB[0][0]); __syncthreads();

    // store channel-major C3[bt][ch][n]
    #pragma unroll
    for (int cc = 0; cc < 4; cc++) {
        float* orow = C3 + ((size_t)bt * CIN + cg * 4 + cc) * NN;
        for (int i = tid; i < NN; i += 1024) orow[i] = bufB[cc][i];
    }
}

// =============== kernel 5: P = C3@W123 + r2*d1 + r1*d2 + b3; out = relu(P), transposed store ===============
// r2 slice recomputed in-block: r2[n] = selfn[n]*r1f[n] + sum val[p]*r1f[col[p]]
__global__ __launch_bounds__(256) void k_out(
    const float* __restrict__ C3,       // [bt][32][2000]
    const float* __restrict__ W123,     // 32x64
    const float* __restrict__ d1, const float* __restrict__ d2,
    const float* __restrict__ b3,
    const float* __restrict__ r1f, const float* __restrict__ selfn,
    const int* __restrict__ rowptr, const int* __restrict__ col,
    const float* __restrict__ val,
    float* __restrict__ out)            // [B][COUT][T][N]
{
    __shared__ float Cs[CIN][65];
    __shared__ float Ws[CIN][64];
    __shared__ float Os[64][65];
    __shared__ float d1s[64], d2s[64], b3s[64], r1s[64], r2s[64];
    const int tid = threadIdx.x;
    const int bt = blockIdx.y, b = bt >> 3, t = bt & 7;
    const int n0 = blockIdx.x * 64;

    for (int i = tid; i < CIN * 64; i += 256) {
        int ch = i >> 6, nn = i & 63;
        int n = n0 + nn;
        Cs[ch][nn] = (n < NN) ? C3[((size_t)bt * CIN + ch) * NN + n] : 0.f;
    }
    for (int i = tid; i < CIN * 64; i += 256)
        Ws[i >> 6][i & 63] = W123[i];
    if (tid < 64) {
        d1s[tid] = d1[tid];
        d2s[tid] = d2[tid];
        b3s[tid] = b3[tid];
        int n = n0 + tid;
        float r1v = 0.f, r2v = 0.f;
        if (n < NN) {
            r1v = r1f[n];
            float acc = selfn[n] * r1v;
            int p0 = rowptr[n], p1 = rowptr[n + 1];
            for (int p = p0; p < p1; p++) acc += val[p] * r1f[col[p]];
            r2v = acc;
        }
        r1s[tid] = r1v;
        r2s[tid] = r2v;
    }
    __syncthreads();

    const int c = tid & 63, g = tid >> 6;
    for (int i = 0; i < 16; i++) {
        int nn = g * 16 + i;
        float acc = r2s[nn] * d1s[c] + r1s[nn] * d2s[c] + b3s[c];
        #pragma unroll
        for (int k = 0; k < CIN; k++) acc += Cs[k][nn] * Ws[k][c];
        Os[nn][c] = fmaxf(acc, 0.f);
    }
    __syncthreads();

    #pragma unroll
    for (int pass = 0; pass < 16; pass++) {
        int cc = g + pass * 4;
        int n = n0 + (tid & 63);
        if (n < NN)
            out[(((size_t)b * COUT + cc) * TT + t) * NN + n] = Os[tid & 63][cc];
    }
}

// ---------------- launch ----------------

extern "C" void kernel_launch(void* const* d_in, const int* in_sizes, int n_in,
                              void* d_out, int out_size, void* d_ws, size_t ws_size,
                              hipStream_t stream) {
    (void)in_sizes; (void)n_in; (void)out_size; (void)ws_size;

    const float* x  = (const float*)d_in[0];
    const int*   ei = (const int*)d_in[1];
    const float* ew = (const float*)d_in[2];
    const float* W1 = (const float*)d_in[3];
    const float* b1 = (const float*)d_in[4];
    const float* W2 = (const float*)d_in[5];
    const float* b2 = (const float*)d_in[6];
    const float* W3 = (const float*)d_in[7];
    const float* b3 = (const float*)d_in[8];
    float* out = (float*)d_out;

    const int* src = ei;
    const int* dst = ei + NE;

    // workspace layout (float units). cnt+deg first => one 16KB memset.
    float* ws     = (float*)d_ws;
    int*   cnt    = (int*)ws;                  // 2048 (atomic accumulator, re-zeroed)
    float* deg    = ws + 2048;                 // 2048 (atomic accumulator, re-zeroed)
    int*   cur    = (int*)(ws + 4096);         // 2048
    int*   rowptr = cur + 2048;                // 2048 (NN+1 used)
    int*   col    = rowptr + 2048;             // NE
    float* val    = (float*)(col + NE);        // NE
    float* dinv   = val + NE;                  // 2048
    float* selfn  = dinv + 2048;               // 2048
    float* r1f    = selfn + 2048;              // 2048
    float* W123   = r1f + 2048;                // 2048
    float* d1     = W123 + 2048;               // 64
    float* d2     = d1 + 64;                   // 64
    float* C3     = d2 + 64 + 64;              // 32*32*2000

    // zero the atomic accumulators (graph-capturable memset node)
    hipMemsetAsync(ws, 0, 4096 * sizeof(float), stream);

    k_count<<<dim3(8 + (NE + 255) / 256), dim3(256), 0, stream>>>(
        src, dst, ew, W1, b1, W2, b2, W3, cnt, deg, W123, d1, d2);

    k_scan<<<dim3(1), dim3(256), 0, stream>>>(cnt, deg, rowptr, cur, dinv, selfn);

    k_fill<<<dim3((NE + 255) / 256), dim3(256), 0, stream>>>(
        src, dst, ew, dinv, cur, col, val);

    k_sss<<<dim3(8, BT), dim3(1024), 0, stream>>>(
        x, rowptr, col, val, selfn, r1f, C3);

    k_out<<<dim3(32, BT), dim3(256), 0, stream>>>(
        C3, W123, d1, d2, b3, r1f, selfn, rowptr, col, val, out);
}